// Round 1
// baseline (188.087 us; speedup 1.0000x reference)
//
#include <hip/hip_runtime.h>
#include <math.h>

// Problem constants
#define TT   4096
#define NBB  32
#define NUU  64
#define NHH  256
#define HH   128
#define NYY  64
// Chunking: 512 chunks of 8 steps; carry hierarchy: 16 supers x 32 chunks
#define LCH  8
#define CCH  512
#define SEGN 16
#define CPS  32

#define PI_HALF 1.5707963267948966f

typedef float  f32x16 __attribute__((ext_vector_type(16)));
typedef __bf16 bf16x8 __attribute__((ext_vector_type(8)));
typedef __bf16 bf16x2 __attribute__((ext_vector_type(2)));
typedef unsigned int uint4v __attribute__((ext_vector_type(4)));

// MFMA 32x32 C/D layout: row = (r&3) + 8*(r>>2) + 4*(lane>>5), col = lane&31
__device__ inline int crow(int r, int lane) { return (r & 3) + 8 * (r >> 2) + 4 * (lane >> 5); }
__device__ inline bf16x8 ldfrag(const unsigned short* p) {
    return __builtin_bit_cast(bf16x8, *(const uint4v*)p);
}

// split a float into bf16 hi + bf16 lo (hi+lo ~ exact to 2^-17 rel)
#define CVT(v, H, L) { __bf16 _h = (__bf16)(v); H = _h; L = (__bf16)((v) - (float)_h); }

// lambda in fp32 exactly as the reference pipeline rounds it, but with
// correctly-rounded transcendentals (double -> fp32)
__device__ inline void lam_f32(float xre, float xim, float& lr, float& li) {
    float th = PI_HALF * xim;
    float rf = (float)exp(-(double)fabsf(xre));
    float cf = (float)cos((double)th);
    float sf = (float)sin((double)th);
    lr = rf * cf; li = rf * sf;
}

// ---------------------------------------------------------------------------
// Prep: x0 pairs; bf16 hi/lo split of B (plain) and W_x2y with interleaved K
// permute: Wp[y][2j] = W[y][j], Wp[y][2j+1] = W[y][j+128].
// ---------------------------------------------------------------------------
__global__ __launch_bounds__(256) void k_prep(
    const float* __restrict__ B, const float* __restrict__ W,
    const float* __restrict__ y0, const float* __restrict__ Wy2x,
    const float* __restrict__ by2x,
    unsigned short* __restrict__ Bph, unsigned short* __restrict__ Bpl,
    unsigned short* __restrict__ Wph, unsigned short* __restrict__ Wpl,
    float2* __restrict__ x0p)
{
    int bx = blockIdx.x, tid = threadIdx.x;
    if (bx < 32) {
        if (tid < HH) {
            int b = bx, ch = tid;
            float xr = by2x[ch], xi = by2x[ch + HH];
            for (int y = 0; y < NYY; ++y) {
                float v = y0[b * NYY + y];
                xr += v * Wy2x[ch * NYY + y];
                xi += v * Wy2x[(ch + HH) * NYY + y];
            }
            x0p[b * HH + ch] = make_float2(xr, xi);
        }
    } else {
        int i = (bx - 32) * 256 + tid;            // 0..16383
        float bv = B[i];
        __bf16 bh = (__bf16)bv;
        Bph[i] = __builtin_bit_cast(unsigned short, bh);
        Bpl[i] = __builtin_bit_cast(unsigned short, (__bf16)(bv - (float)bh));
        int y = i >> 8, kidx = i & 255;
        float wv = W[y * NHH + (kidx & 1) * HH + (kidx >> 1)];
        __bf16 wh = (__bf16)wv;
        Wph[i] = __builtin_bit_cast(unsigned short, wh);
        Wpl[i] = __builtin_bit_cast(unsigned short, (__bf16)(wv - (float)wh));
    }
}

// ---------------------------------------------------------------------------
// Pass 1: per-chunk (L=8) local end state E_c. Wave w owns channel-pair tiles
// (re rows j=w*32.., im rows 128+j) -> lane holds (zr,zi) of one channel.
// Split-bf16 Bu: acc += Uhi*Bhi + Ulo*Bhi + Uhi*Blo  (12 MFMA / kk).
// ---------------------------------------------------------------------------
__global__ __launch_bounds__(256, 2) void k_pass1(
    const float* __restrict__ U,
    const unsigned short* __restrict__ Bph, const unsigned short* __restrict__ Bpl,
    const float* __restrict__ lre, const float* __restrict__ lim,
    float2* __restrict__ E)
{
    __shared__ __align__(16) unsigned short sU[64 * 136];   // [row][hi 64 | lo 64 | pad 8]

    const int tid = threadIdx.x, w = tid >> 6, lane = tid & 63;
    const int l31 = lane & 31, kh = lane >> 5;
    const int c = blockIdx.x;
    const int ch = w * 32 + l31;

    float lr, li; lam_f32(lre[ch], lim[ch], lr, li);

    // Hoist B fragments (hi and lo): nt=0 -> re rows, nt=1 -> im rows
    bf16x8 bfh[2][4], bfl[2][4];
#pragma unroll
    for (int nt = 0; nt < 2; ++nt)
#pragma unroll
        for (int kk = 0; kk < 4; ++kk) {
            bfh[nt][kk] = ldfrag(&Bph[(size_t)(nt * HH + ch) * NUU + kk * 16 + kh * 8]);
            bfl[nt][kk] = ldfrag(&Bpl[(size_t)(nt * HH + ch) * NUU + kk * 16 + kh * 8]);
        }

    float zr[16], zi[16];
#pragma unroll
    for (int r = 0; r < 16; ++r) { zr[r] = 0.f; zi[r] = 0.f; }

    for (int sub = 0; sub < 4; ++sub) {
        {   // stage U (2 t x 32 b x 64 u) as split-bf16
            int row = tid >> 2, us = (tid & 3) * 16;
            int t = c * LCH + sub * 2 + (row >> 5), b = row & 31;
            const float4* s = (const float4*)(U + ((size_t)t * NBB + b) * NUU + us);
            float4 f0 = s[0], f1 = s[1], f2 = s[2], f3 = s[3];
            bf16x8 h0, h1, l0, l1;
            CVT(f0.x, h0[0], l0[0]); CVT(f0.y, h0[1], l0[1]); CVT(f0.z, h0[2], l0[2]); CVT(f0.w, h0[3], l0[3]);
            CVT(f1.x, h0[4], l0[4]); CVT(f1.y, h0[5], l0[5]); CVT(f1.z, h0[6], l0[6]); CVT(f1.w, h0[7], l0[7]);
            CVT(f2.x, h1[0], l1[0]); CVT(f2.y, h1[1], l1[1]); CVT(f2.z, h1[2], l1[2]); CVT(f2.w, h1[3], l1[3]);
            CVT(f3.x, h1[4], l1[4]); CVT(f3.y, h1[5], l1[5]); CVT(f3.z, h1[6], l1[6]); CVT(f3.w, h1[7], l1[7]);
            *(bf16x8*)&sU[row * 136 + us]          = h0;
            *(bf16x8*)&sU[row * 136 + us + 8]      = h1;
            *(bf16x8*)&sU[row * 136 + 64 + us]     = l0;
            *(bf16x8*)&sU[row * 136 + 64 + us + 8] = l1;
        }
        __syncthreads();

        f32x16 acc[2][2];
#pragma unroll
        for (int mt = 0; mt < 2; ++mt)
#pragma unroll
            for (int nt = 0; nt < 2; ++nt)
#pragma unroll
                for (int r = 0; r < 16; ++r) acc[mt][nt][r] = 0.f;

#pragma unroll
        for (int kk = 0; kk < 4; ++kk) {
            bf16x8 a0h = ldfrag(&sU[(l31)      * 136 + kk * 16 + kh * 8]);
            bf16x8 a1h = ldfrag(&sU[(32 + l31) * 136 + kk * 16 + kh * 8]);
            bf16x8 a0l = ldfrag(&sU[(l31)      * 136 + 64 + kk * 16 + kh * 8]);
            bf16x8 a1l = ldfrag(&sU[(32 + l31) * 136 + 64 + kk * 16 + kh * 8]);
            acc[0][0] = __builtin_amdgcn_mfma_f32_32x32x16_bf16(a0h, bfh[0][kk], acc[0][0], 0, 0, 0);
            acc[0][1] = __builtin_amdgcn_mfma_f32_32x32x16_bf16(a0h, bfh[1][kk], acc[0][1], 0, 0, 0);
            acc[1][0] = __builtin_amdgcn_mfma_f32_32x32x16_bf16(a1h, bfh[0][kk], acc[1][0], 0, 0, 0);
            acc[1][1] = __builtin_amdgcn_mfma_f32_32x32x16_bf16(a1h, bfh[1][kk], acc[1][1], 0, 0, 0);
            acc[0][0] = __builtin_amdgcn_mfma_f32_32x32x16_bf16(a0l, bfh[0][kk], acc[0][0], 0, 0, 0);
            acc[0][1] = __builtin_amdgcn_mfma_f32_32x32x16_bf16(a0l, bfh[1][kk], acc[0][1], 0, 0, 0);
            acc[1][0] = __builtin_amdgcn_mfma_f32_32x32x16_bf16(a1l, bfh[0][kk], acc[1][0], 0, 0, 0);
            acc[1][1] = __builtin_amdgcn_mfma_f32_32x32x16_bf16(a1l, bfh[1][kk], acc[1][1], 0, 0, 0);
            acc[0][0] = __builtin_amdgcn_mfma_f32_32x32x16_bf16(a0h, bfl[0][kk], acc[0][0], 0, 0, 0);
            acc[0][1] = __builtin_amdgcn_mfma_f32_32x32x16_bf16(a0h, bfl[1][kk], acc[0][1], 0, 0, 0);
            acc[1][0] = __builtin_amdgcn_mfma_f32_32x32x16_bf16(a1h, bfl[0][kk], acc[1][0], 0, 0, 0);
            acc[1][1] = __builtin_amdgcn_mfma_f32_32x32x16_bf16(a1h, bfl[1][kk], acc[1][1], 0, 0, 0);
        }

#pragma unroll
        for (int mt = 0; mt < 2; ++mt)
#pragma unroll
            for (int r = 0; r < 16; ++r) {
                float t0 = fmaf(lr, zr[r], acc[mt][0][r]); t0 = fmaf(-li, zi[r], t0);
                float t1 = fmaf(li, zr[r], acc[mt][1][r]); t1 = fmaf(lr, zi[r], t1);
                zr[r] = t0; zi[r] = t1;
            }
        __syncthreads();
    }

#pragma unroll
    for (int r = 0; r < 16; ++r)
        E[(size_t)c * 4096 + crow(r, lane) * HH + ch] = make_float2(zr[r], zi[r]);
}

// ---------------------------------------------------------------------------
// Carry hierarchy. chain = b*128 + ch (4096 chains). Powers of the fp32
// lambda computed EXACTLY (double squaring), recurrences in double.
// ---------------------------------------------------------------------------
__global__ __launch_bounds__(256) void k_cseg(
    const float* __restrict__ lre, const float* __restrict__ lim,
    const float2* __restrict__ E, float2* __restrict__ Esup)
{
    int g = blockIdx.x * 256 + threadIdx.x;
    int chain = g & 4095, seg = g >> 12, ch = chain & 127;
    float lrf, lif; lam_f32(lre[ch], lim[ch], lrf, lif);
    double pr = (double)lrf, pi = (double)lif;
#pragma unroll
    for (int s = 0; s < 3; ++s) { double nr = pr*pr - pi*pi, ni = 2.0*pr*pi; pr = nr; pi = ni; } // lambda^8
    double sr = 0.0, si = 0.0;
#pragma unroll 8
    for (int j = 0; j < CPS; ++j) {
        float2 e = E[((size_t)seg * CPS + j) * 4096 + chain];
        double nr = pr * sr - pi * si + (double)e.x;
        double ni = pi * sr + pr * si + (double)e.y;
        sr = nr; si = ni;
    }
    Esup[(size_t)seg * 4096 + chain] = make_float2((float)sr, (float)si);
}

__global__ __launch_bounds__(256) void k_csup(
    const float* __restrict__ lre, const float* __restrict__ lim,
    const float2* __restrict__ x0p, const float2* __restrict__ Esup,
    float2* __restrict__ CarrySup)
{
    int chain = blockIdx.x * 256 + threadIdx.x;   // grid 16 -> 0..4095
    int ch = chain & 127;
    float lrf, lif; lam_f32(lre[ch], lim[ch], lrf, lif);
    double pr = (double)lrf, pi = (double)lif;
#pragma unroll
    for (int s = 0; s < 8; ++s) { double nr = pr*pr - pi*pi, ni = 2.0*pr*pi; pr = nr; pi = ni; } // lambda^256
    float2 c0 = x0p[chain];
    double cr = (double)c0.x, ci = (double)c0.y;
#pragma unroll
    for (int s = 0; s < SEGN; ++s) {
        CarrySup[(size_t)s * 4096 + chain] = make_float2((float)cr, (float)ci);
        float2 e = Esup[(size_t)s * 4096 + chain];
        double nr = pr * cr - pi * ci + (double)e.x;
        double ni = pi * cr + pr * ci + (double)e.y;
        cr = nr; ci = ni;
    }
}

__global__ __launch_bounds__(256) void k_cexp(
    const float* __restrict__ lre, const float* __restrict__ lim,
    const float2* __restrict__ E, const float2* __restrict__ CarrySup,
    float2* __restrict__ Carry)
{
    int g = blockIdx.x * 256 + threadIdx.x;
    int chain = g & 4095, seg = g >> 12, ch = chain & 127;
    float lrf, lif; lam_f32(lre[ch], lim[ch], lrf, lif);
    double pr = (double)lrf, pi = (double)lif;
#pragma unroll
    for (int s = 0; s < 3; ++s) { double nr = pr*pr - pi*pi, ni = 2.0*pr*pi; pr = nr; pi = ni; } // lambda^8
    float2 cc = CarrySup[(size_t)seg * 4096 + chain];
    double cr = (double)cc.x, ci = (double)cc.y;
#pragma unroll 8
    for (int j = 0; j < CPS; ++j) {
        size_t idx = ((size_t)seg * CPS + j) * 4096 + chain;
        Carry[idx] = make_float2((float)cr, (float)ci);
        float2 e = E[idx];
        double nr = pr * cr - pi * ci + (double)e.x;
        double ni = pi * cr + pr * ci + (double)e.y;
        cr = nr; ci = ni;
    }
}

// ---------------------------------------------------------------------------
// Pass 2: seeded scan + fused output GEMM, both split-bf16.
// Per sub: [stage-loads -> out-GEMM(sub-1) -> convert+ds_write] -> barrier
//          -> [Bu MFMA (3-term) + scan + split dump into sX] -> barrier.
// sX row = [hi 256 | lo 256 | pad 8]; columns interleaved (2j=re, 2j+1=im).
// W fragments (hi+lo) hoisted to registers once per block.
// LDS = 17.4 + 66.6 = 82 KB -> 1 block/CU; launch_bounds(256,1) for regs.
// ---------------------------------------------------------------------------
__global__ __launch_bounds__(256, 1) void k_pass2(
    const float* __restrict__ U,
    const unsigned short* __restrict__ Bph, const unsigned short* __restrict__ Bpl,
    const unsigned short* __restrict__ Wph, const unsigned short* __restrict__ Wpl,
    const float* __restrict__ lre, const float* __restrict__ lim,
    const float* __restrict__ bx2y,
    const float2* __restrict__ Carry, float* __restrict__ Y)
{
    __shared__ __align__(16) unsigned short sU[64 * 136];   // 17.4 KB
    __shared__ __align__(16) unsigned short sX[64 * 520];   // 66.6 KB

    const int tid = threadIdx.x, w = tid >> 6, lane = tid & 63;
    const int l31 = lane & 31, kh = lane >> 5;
    const int c = blockIdx.x;
    const int ch = w * 32 + l31;             // scan channel
    const int mtile = w & 1, ntile = w >> 1; // out-GEMM tile mapping

    float lr, li; lam_f32(lre[ch], lim[ch], lr, li);
    float ybias = bx2y[ntile * 32 + l31];

    bf16x8 bfh[2][4], bfl[2][4];
#pragma unroll
    for (int nt = 0; nt < 2; ++nt)
#pragma unroll
        for (int kk = 0; kk < 4; ++kk) {
            bfh[nt][kk] = ldfrag(&Bph[(size_t)(nt * HH + ch) * NUU + kk * 16 + kh * 8]);
            bfl[nt][kk] = ldfrag(&Bpl[(size_t)(nt * HH + ch) * NUU + kk * 16 + kh * 8]);
        }

    // Hoist W fragments (hi + lo) once per block
    bf16x8 wfh[16], wfl[16];
#pragma unroll
    for (int kk = 0; kk < 16; ++kk) {
        wfh[kk] = ldfrag(&Wph[(size_t)(ntile * 32 + l31) * NHH + kk * 16 + kh * 8]);
        wfl[kk] = ldfrag(&Wpl[(size_t)(ntile * 32 + l31) * NHH + kk * 16 + kh * 8]);
    }

    // Seed from Carry
    float zr[16], zi[16];
#pragma unroll
    for (int r = 0; r < 16; ++r) {
        float2 v = Carry[(size_t)c * 4096 + crow(r, lane) * HH + ch];
        zr[r] = v.x; zi[r] = v.y;
    }

    for (int sub = 0; sub < 4; ++sub) {
        // issue stage loads first (latency hides under out-GEMM)
        int srow = tid >> 2, sus = (tid & 3) * 16;
        int st = c * LCH + sub * 2 + (srow >> 5), sb = srow & 31;
        const float4* sp = (const float4*)(U + ((size_t)st * NBB + sb) * NUU + sus);
        float4 f0 = sp[0], f1 = sp[1], f2 = sp[2], f3 = sp[3];

        if (sub > 0) {  // out-GEMM for sub-1 (reads sX written before last barrier)
            f32x16 ya0, ya1, ya2;
#pragma unroll
            for (int r = 0; r < 16; ++r) { ya0[r] = 0.f; ya1[r] = 0.f; ya2[r] = 0.f; }
#pragma unroll
            for (int kk = 0; kk < 16; ++kk) {
                bf16x8 xah = ldfrag(&sX[(mtile * 32 + l31) * 520 + kk * 16 + kh * 8]);
                bf16x8 xal = ldfrag(&sX[(mtile * 32 + l31) * 520 + 256 + kk * 16 + kh * 8]);
                ya0 = __builtin_amdgcn_mfma_f32_32x32x16_bf16(xah, wfh[kk], ya0, 0, 0, 0);
                ya1 = __builtin_amdgcn_mfma_f32_32x32x16_bf16(xal, wfh[kk], ya1, 0, 0, 0);
                ya2 = __builtin_amdgcn_mfma_f32_32x32x16_bf16(xah, wfl[kk], ya2, 0, 0, 0);
            }
            int t = c * LCH + (sub - 1) * 2 + mtile;
#pragma unroll
            for (int r = 0; r < 16; ++r)
                Y[((size_t)t * NBB + crow(r, lane)) * NYY + ntile * 32 + l31] =
                    (ya0[r] + ya1[r]) + ya2[r] + ybias;
        }

        {   // convert + ds_write the staged tile
            bf16x8 h0, h1, l0, l1;
            CVT(f0.x, h0[0], l0[0]); CVT(f0.y, h0[1], l0[1]); CVT(f0.z, h0[2], l0[2]); CVT(f0.w, h0[3], l0[3]);
            CVT(f1.x, h0[4], l0[4]); CVT(f1.y, h0[5], l0[5]); CVT(f1.z, h0[6], l0[6]); CVT(f1.w, h0[7], l0[7]);
            CVT(f2.x, h1[0], l1[0]); CVT(f2.y, h1[1], l1[1]); CVT(f2.z, h1[2], l1[2]); CVT(f2.w, h1[3], l1[3]);
            CVT(f3.x, h1[4], l1[4]); CVT(f3.y, h1[5], l1[5]); CVT(f3.z, h1[6], l1[6]); CVT(f3.w, h1[7], l1[7]);
            *(bf16x8*)&sU[srow * 136 + sus]          = h0;
            *(bf16x8*)&sU[srow * 136 + sus + 8]      = h1;
            *(bf16x8*)&sU[srow * 136 + 64 + sus]     = l0;
            *(bf16x8*)&sU[srow * 136 + 64 + sus + 8] = l1;
        }
        __syncthreads();

        // Bu MFMA (split 3-term)
        f32x16 acc[2][2];
#pragma unroll
        for (int mt = 0; mt < 2; ++mt)
#pragma unroll
            for (int nt = 0; nt < 2; ++nt)
#pragma unroll
                for (int r = 0; r < 16; ++r) acc[mt][nt][r] = 0.f;

#pragma unroll
        for (int kk = 0; kk < 4; ++kk) {
            bf16x8 a0h = ldfrag(&sU[(l31)      * 136 + kk * 16 + kh * 8]);
            bf16x8 a1h = ldfrag(&sU[(32 + l31) * 136 + kk * 16 + kh * 8]);
            bf16x8 a0l = ldfrag(&sU[(l31)      * 136 + 64 + kk * 16 + kh * 8]);
            bf16x8 a1l = ldfrag(&sU[(32 + l31) * 136 + 64 + kk * 16 + kh * 8]);
            acc[0][0] = __builtin_amdgcn_mfma_f32_32x32x16_bf16(a0h, bfh[0][kk], acc[0][0], 0, 0, 0);
            acc[0][1] = __builtin_amdgcn_mfma_f32_32x32x16_bf16(a0h, bfh[1][kk], acc[0][1], 0, 0, 0);
            acc[1][0] = __builtin_amdgcn_mfma_f32_32x32x16_bf16(a1h, bfh[0][kk], acc[1][0], 0, 0, 0);
            acc[1][1] = __builtin_amdgcn_mfma_f32_32x32x16_bf16(a1h, bfh[1][kk], acc[1][1], 0, 0, 0);
            acc[0][0] = __builtin_amdgcn_mfma_f32_32x32x16_bf16(a0l, bfh[0][kk], acc[0][0], 0, 0, 0);
            acc[0][1] = __builtin_amdgcn_mfma_f32_32x32x16_bf16(a0l, bfh[1][kk], acc[0][1], 0, 0, 0);
            acc[1][0] = __builtin_amdgcn_mfma_f32_32x32x16_bf16(a1l, bfh[0][kk], acc[1][0], 0, 0, 0);
            acc[1][1] = __builtin_amdgcn_mfma_f32_32x32x16_bf16(a1l, bfh[1][kk], acc[1][1], 0, 0, 0);
            acc[0][0] = __builtin_amdgcn_mfma_f32_32x32x16_bf16(a0h, bfl[0][kk], acc[0][0], 0, 0, 0);
            acc[0][1] = __builtin_amdgcn_mfma_f32_32x32x16_bf16(a0h, bfl[1][kk], acc[0][1], 0, 0, 0);
            acc[1][0] = __builtin_amdgcn_mfma_f32_32x32x16_bf16(a1h, bfl[0][kk], acc[1][0], 0, 0, 0);
            acc[1][1] = __builtin_amdgcn_mfma_f32_32x32x16_bf16(a1h, bfl[1][kk], acc[1][1], 0, 0, 0);
        }

        // Scan + split hi/lo dump (two b32 per (mt,r))
#pragma unroll
        for (int mt = 0; mt < 2; ++mt)
#pragma unroll
            for (int r = 0; r < 16; ++r) {
                float t0 = fmaf(lr, zr[r], acc[mt][0][r]); t0 = fmaf(-li, zi[r], t0);
                float t1 = fmaf(li, zr[r], acc[mt][1][r]); t1 = fmaf(lr, zi[r], t1);
                zr[r] = t0; zi[r] = t1;
                bf16x2 hv, lv;
                { __bf16 _h = (__bf16)t0; hv[0] = _h; lv[0] = (__bf16)(t0 - (float)_h); }
                { __bf16 _h = (__bf16)t1; hv[1] = _h; lv[1] = (__bf16)(t1 - (float)_h); }
                int rowb = (mt * 32 + crow(r, lane)) * 520;
                *(bf16x2*)&sX[rowb + w * 64 + 2 * l31]       = hv;
                *(bf16x2*)&sX[rowb + 256 + w * 64 + 2 * l31] = lv;
            }
        __syncthreads();
    }

    // Drain: out-GEMM for sub=3
    {
        f32x16 ya0, ya1, ya2;
#pragma unroll
        for (int r = 0; r < 16; ++r) { ya0[r] = 0.f; ya1[r] = 0.f; ya2[r] = 0.f; }
#pragma unroll
        for (int kk = 0; kk < 16; ++kk) {
            bf16x8 xah = ldfrag(&sX[(mtile * 32 + l31) * 520 + kk * 16 + kh * 8]);
            bf16x8 xal = ldfrag(&sX[(mtile * 32 + l31) * 520 + 256 + kk * 16 + kh * 8]);
            ya0 = __builtin_amdgcn_mfma_f32_32x32x16_bf16(xah, wfh[kk], ya0, 0, 0, 0);
            ya1 = __builtin_amdgcn_mfma_f32_32x32x16_bf16(xal, wfh[kk], ya1, 0, 0, 0);
            ya2 = __builtin_amdgcn_mfma_f32_32x32x16_bf16(xah, wfl[kk], ya2, 0, 0, 0);
        }
        int t = c * LCH + 3 * 2 + mtile;
#pragma unroll
        for (int r = 0; r < 16; ++r)
            Y[((size_t)t * NBB + crow(r, lane)) * NYY + ntile * 32 + l31] =
                (ya0[r] + ya1[r]) + ya2[r] + ybias;
    }
}

// ---------------------------------------------------------------------------
extern "C" void kernel_launch(void* const* d_in, const int* in_sizes, int n_in,
                              void* d_out, int out_size, void* d_ws, size_t ws_size,
                              hipStream_t stream) {
    const float* y0    = (const float*)d_in[0];
    const float* U     = (const float*)d_in[1];
    const float* lre   = (const float*)d_in[2];
    const float* lim   = (const float*)d_in[3];
    const float* B     = (const float*)d_in[4];
    const float* W_y2x = (const float*)d_in[5];
    const float* b_y2x = (const float*)d_in[6];
    const float* W_x2y = (const float*)d_in[7];
    const float* b_x2y = (const float*)d_in[8];
    float* Y = (float*)d_out;

    char* p = (char*)d_ws;
    float2* E        = (float2*)p; p += (size_t)CCH * 4096 * sizeof(float2);   // 16 MB
    float2* Carry    = (float2*)p; p += (size_t)CCH * 4096 * sizeof(float2);   // 16 MB
    float2* Esup     = (float2*)p; p += (size_t)SEGN * 4096 * sizeof(float2);  // 512 KB
    float2* CarrySup = (float2*)p; p += (size_t)SEGN * 4096 * sizeof(float2);  // 512 KB
    float2* x0p      = (float2*)p; p += (size_t)4096 * sizeof(float2);         // 32 KB
    unsigned short* Bph = (unsigned short*)p; p += 16384 * sizeof(unsigned short);
    unsigned short* Bpl = (unsigned short*)p; p += 16384 * sizeof(unsigned short);
    unsigned short* Wph = (unsigned short*)p; p += 16384 * sizeof(unsigned short);
    unsigned short* Wpl = (unsigned short*)p; p += 16384 * sizeof(unsigned short);

    k_prep <<<dim3(96),  dim3(256), 0, stream>>>(B, W_x2y, y0, W_y2x, b_y2x, Bph, Bpl, Wph, Wpl, x0p);
    k_pass1<<<dim3(CCH), dim3(256), 0, stream>>>(U, Bph, Bpl, lre, lim, E);
    k_cseg <<<dim3(256), dim3(256), 0, stream>>>(lre, lim, E, Esup);
    k_csup <<<dim3(16),  dim3(256), 0, stream>>>(lre, lim, x0p, Esup, CarrySup);
    k_cexp <<<dim3(256), dim3(256), 0, stream>>>(lre, lim, E, CarrySup, Carry);
    k_pass2<<<dim3(CCH), dim3(256), 0, stream>>>(U, Bph, Bpl, Wph, Wpl, lre, lim, b_x2y, Carry, Y);
}

// Round 2
// 172.923 us; speedup vs baseline: 1.0877x; 1.0877x over previous
//
#include <hip/hip_runtime.h>
#include <math.h>

// Problem constants
#define TT   4096
#define NBB  32
#define NUU  64
#define NHH  256
#define HH   128
#define NYY  64
// Chunking: 512 chunks of 8 steps; carry hierarchy: 16 supers x 32 chunks
#define LCH  8
#define CCH  512
#define SEGN 16
#define CPS  32

#define PI_HALF 1.5707963267948966f

typedef float  f32x16 __attribute__((ext_vector_type(16)));
typedef __bf16 bf16x8 __attribute__((ext_vector_type(8)));
typedef __bf16 bf16x2 __attribute__((ext_vector_type(2)));
typedef unsigned int uint4v __attribute__((ext_vector_type(4)));

// MFMA 32x32 C/D layout: row = (r&3) + 8*(r>>2) + 4*(lane>>5), col = lane&31
__device__ inline int crow(int r, int lane) { return (r & 3) + 8 * (r >> 2) + 4 * (lane >> 5); }
__device__ inline bf16x8 ldfrag(const unsigned short* p) {
    return __builtin_bit_cast(bf16x8, *(const uint4v*)p);
}

// split a float into bf16 hi + bf16 lo (hi+lo ~ exact to 2^-17 rel)
#define CVT(v, H, L) { __bf16 _h = (__bf16)(v); H = _h; L = (__bf16)((v) - (float)_h); }

// lambda in fp32 with correctly-rounded transcendentals (double -> fp32)
__device__ inline void lam_f32(float xre, float xim, float& lr, float& li) {
    float th = PI_HALF * xim;
    float rf = (float)exp(-(double)fabsf(xre));
    float cf = (float)cos((double)th);
    float sf = (float)sin((double)th);
    lr = rf * cf; li = rf * sf;
}

// --- swizzled LDS index helpers (offsets in shorts, 16B chunk = 8 shorts) ---
// sU: row stride 128 shorts (256 B, zero pad); chunk ^= row&15 (bijective)
__device__ inline int swzU(int row, int so) {
    return row * 128 + ((((so >> 3) ^ row) & 15) << 3) + (so & 7);
}
// sX: row stride 512 shorts (1024 B, zero pad); low-5 of chunk ^= row&31, bit5 kept
__device__ inline int swzX(int row, int so) {
    int chv = so >> 3;
    chv = (chv & 32) | ((chv ^ row) & 31);
    return row * 512 + (chv << 3) + (so & 7);
}

// ---------------------------------------------------------------------------
// Prep: x0 pairs; bf16 hi/lo split of B (plain) and W_x2y with interleaved K
// permute: Wp[y][2j] = W[y][j], Wp[y][2j+1] = W[y][j+128].
// ---------------------------------------------------------------------------
__global__ __launch_bounds__(256) void k_prep(
    const float* __restrict__ B, const float* __restrict__ W,
    const float* __restrict__ y0, const float* __restrict__ Wy2x,
    const float* __restrict__ by2x,
    unsigned short* __restrict__ Bph, unsigned short* __restrict__ Bpl,
    unsigned short* __restrict__ Wph, unsigned short* __restrict__ Wpl,
    float2* __restrict__ x0p)
{
    int bx = blockIdx.x, tid = threadIdx.x;
    if (bx < 32) {
        if (tid < HH) {
            int b = bx, ch = tid;
            float xr = by2x[ch], xi = by2x[ch + HH];
            for (int y = 0; y < NYY; ++y) {
                float v = y0[b * NYY + y];
                xr += v * Wy2x[ch * NYY + y];
                xi += v * Wy2x[(ch + HH) * NYY + y];
            }
            x0p[b * HH + ch] = make_float2(xr, xi);
        }
    } else {
        int i = (bx - 32) * 256 + tid;            // 0..16383
        float bv = B[i];
        __bf16 bh = (__bf16)bv;
        Bph[i] = __builtin_bit_cast(unsigned short, bh);
        Bpl[i] = __builtin_bit_cast(unsigned short, (__bf16)(bv - (float)bh));
        int y = i >> 8, kidx = i & 255;
        float wv = W[y * NHH + (kidx & 1) * HH + (kidx >> 1)];
        __bf16 wh = (__bf16)wv;
        Wph[i] = __builtin_bit_cast(unsigned short, wh);
        Wpl[i] = __builtin_bit_cast(unsigned short, (__bf16)(wv - (float)wh));
    }
}

// ---------------------------------------------------------------------------
// Pass 1: per-chunk (L=8) local end state E_c.
// v2: launch_bounds(256,1) (kill the 128-VGPR spill cap), double-buffered sU
// (one barrier per sub), U(sub+1) prefetched into regs during MFMA phase.
// ---------------------------------------------------------------------------
__global__ __launch_bounds__(256, 1) void k_pass1(
    const float* __restrict__ U,
    const unsigned short* __restrict__ Bph, const unsigned short* __restrict__ Bpl,
    const float* __restrict__ lre, const float* __restrict__ lim,
    float2* __restrict__ E)
{
    __shared__ __align__(16) unsigned short sU[2][64 * 136];   // 2 x 17.4 KB

    const int tid = threadIdx.x, w = tid >> 6, lane = tid & 63;
    const int l31 = lane & 31, kh = lane >> 5;
    const int c = blockIdx.x;
    const int ch = w * 32 + l31;

    float lr, li; lam_f32(lre[ch], lim[ch], lr, li);

    // Hoist B fragments (hi and lo): nt=0 -> re rows, nt=1 -> im rows
    bf16x8 bfh[2][4], bfl[2][4];
#pragma unroll
    for (int nt = 0; nt < 2; ++nt)
#pragma unroll
        for (int kk = 0; kk < 4; ++kk) {
            bfh[nt][kk] = ldfrag(&Bph[(size_t)(nt * HH + ch) * NUU + kk * 16 + kh * 8]);
            bfl[nt][kk] = ldfrag(&Bpl[(size_t)(nt * HH + ch) * NUU + kk * 16 + kh * 8]);
        }

    float zr[16], zi[16];
#pragma unroll
    for (int r = 0; r < 16; ++r) { zr[r] = 0.f; zi[r] = 0.f; }

    const int srow = tid >> 2, sus = (tid & 3) * 16;
    const int sb = srow & 31, stoff = srow >> 5;
    const float* ubase = U + (size_t)sb * NUU + sus;

    // prefetch sub 0
    float4 f0, f1, f2, f3;
    {
        const float4* sp = (const float4*)(ubase + (size_t)(c * LCH + stoff) * (NBB * NUU));
        f0 = sp[0]; f1 = sp[1]; f2 = sp[2]; f3 = sp[3];
    }

    for (int sub = 0; sub < 4; ++sub) {
        unsigned short* su = &sU[sub & 1][0];
        {   // convert staged regs -> split-bf16, write LDS
            bf16x8 h0, h1, l0, l1;
            CVT(f0.x, h0[0], l0[0]); CVT(f0.y, h0[1], l0[1]); CVT(f0.z, h0[2], l0[2]); CVT(f0.w, h0[3], l0[3]);
            CVT(f1.x, h0[4], l0[4]); CVT(f1.y, h0[5], l0[5]); CVT(f1.z, h0[6], l0[6]); CVT(f1.w, h0[7], l0[7]);
            CVT(f2.x, h1[0], l1[0]); CVT(f2.y, h1[1], l1[1]); CVT(f2.z, h1[2], l1[2]); CVT(f2.w, h1[3], l1[3]);
            CVT(f3.x, h1[4], l1[4]); CVT(f3.y, h1[5], l1[5]); CVT(f3.z, h1[6], l1[6]); CVT(f3.w, h1[7], l1[7]);
            *(bf16x8*)&su[srow * 136 + sus]          = h0;
            *(bf16x8*)&su[srow * 136 + sus + 8]      = h1;
            *(bf16x8*)&su[srow * 136 + 64 + sus]     = l0;
            *(bf16x8*)&su[srow * 136 + 64 + sus + 8] = l1;
        }
        __syncthreads();

        if (sub < 3) {   // prefetch next sub while MFMA runs
            const float4* sp = (const float4*)(ubase + (size_t)(c * LCH + (sub + 1) * 2 + stoff) * (NBB * NUU));
            f0 = sp[0]; f1 = sp[1]; f2 = sp[2]; f3 = sp[3];
        }

        f32x16 acc[2][2];
#pragma unroll
        for (int mt = 0; mt < 2; ++mt)
#pragma unroll
            for (int nt = 0; nt < 2; ++nt)
#pragma unroll
                for (int r = 0; r < 16; ++r) acc[mt][nt][r] = 0.f;

#pragma unroll
        for (int kk = 0; kk < 4; ++kk) {
            bf16x8 a0h = ldfrag(&su[(l31)      * 136 + kk * 16 + kh * 8]);
            bf16x8 a1h = ldfrag(&su[(32 + l31) * 136 + kk * 16 + kh * 8]);
            bf16x8 a0l = ldfrag(&su[(l31)      * 136 + 64 + kk * 16 + kh * 8]);
            bf16x8 a1l = ldfrag(&su[(32 + l31) * 136 + 64 + kk * 16 + kh * 8]);
            acc[0][0] = __builtin_amdgcn_mfma_f32_32x32x16_bf16(a0h, bfh[0][kk], acc[0][0], 0, 0, 0);
            acc[0][1] = __builtin_amdgcn_mfma_f32_32x32x16_bf16(a0h, bfh[1][kk], acc[0][1], 0, 0, 0);
            acc[1][0] = __builtin_amdgcn_mfma_f32_32x32x16_bf16(a1h, bfh[0][kk], acc[1][0], 0, 0, 0);
            acc[1][1] = __builtin_amdgcn_mfma_f32_32x32x16_bf16(a1h, bfh[1][kk], acc[1][1], 0, 0, 0);
            acc[0][0] = __builtin_amdgcn_mfma_f32_32x32x16_bf16(a0l, bfh[0][kk], acc[0][0], 0, 0, 0);
            acc[0][1] = __builtin_amdgcn_mfma_f32_32x32x16_bf16(a0l, bfh[1][kk], acc[0][1], 0, 0, 0);
            acc[1][0] = __builtin_amdgcn_mfma_f32_32x32x16_bf16(a1l, bfh[0][kk], acc[1][0], 0, 0, 0);
            acc[1][1] = __builtin_amdgcn_mfma_f32_32x32x16_bf16(a1l, bfh[1][kk], acc[1][1], 0, 0, 0);
            acc[0][0] = __builtin_amdgcn_mfma_f32_32x32x16_bf16(a0h, bfl[0][kk], acc[0][0], 0, 0, 0);
            acc[0][1] = __builtin_amdgcn_mfma_f32_32x32x16_bf16(a0h, bfl[1][kk], acc[0][1], 0, 0, 0);
            acc[1][0] = __builtin_amdgcn_mfma_f32_32x32x16_bf16(a1h, bfl[0][kk], acc[1][0], 0, 0, 0);
            acc[1][1] = __builtin_amdgcn_mfma_f32_32x32x16_bf16(a1h, bfl[1][kk], acc[1][1], 0, 0, 0);
        }

#pragma unroll
        for (int mt = 0; mt < 2; ++mt)
#pragma unroll
            for (int r = 0; r < 16; ++r) {
                float t0 = fmaf(lr, zr[r], acc[mt][0][r]); t0 = fmaf(-li, zi[r], t0);
                float t1 = fmaf(li, zr[r], acc[mt][1][r]); t1 = fmaf(lr, zi[r], t1);
                zr[r] = t0; zi[r] = t1;
            }
        // no trailing barrier: next sub writes the other buffer
    }

#pragma unroll
    for (int r = 0; r < 16; ++r)
        E[(size_t)c * 4096 + crow(r, lane) * HH + ch] = make_float2(zr[r], zi[r]);
}

// ---------------------------------------------------------------------------
// Carry hierarchy. chain = b*128 + ch (4096 chains). Powers of the fp32
// lambda computed EXACTLY (double squaring), recurrences in double.
// ---------------------------------------------------------------------------
__global__ __launch_bounds__(256) void k_cseg(
    const float* __restrict__ lre, const float* __restrict__ lim,
    const float2* __restrict__ E, float2* __restrict__ Esup)
{
    int g = blockIdx.x * 256 + threadIdx.x;
    int chain = g & 4095, seg = g >> 12, ch = chain & 127;
    float lrf, lif; lam_f32(lre[ch], lim[ch], lrf, lif);
    double pr = (double)lrf, pi = (double)lif;
#pragma unroll
    for (int s = 0; s < 3; ++s) { double nr = pr*pr - pi*pi, ni = 2.0*pr*pi; pr = nr; pi = ni; } // lambda^8
    double sr = 0.0, si = 0.0;
#pragma unroll 8
    for (int j = 0; j < CPS; ++j) {
        float2 e = E[((size_t)seg * CPS + j) * 4096 + chain];
        double nr = pr * sr - pi * si + (double)e.x;
        double ni = pi * sr + pr * si + (double)e.y;
        sr = nr; si = ni;
    }
    Esup[(size_t)seg * 4096 + chain] = make_float2((float)sr, (float)si);
}

__global__ __launch_bounds__(256) void k_csup(
    const float* __restrict__ lre, const float* __restrict__ lim,
    const float2* __restrict__ x0p, const float2* __restrict__ Esup,
    float2* __restrict__ CarrySup)
{
    int chain = blockIdx.x * 256 + threadIdx.x;   // grid 16 -> 0..4095
    int ch = chain & 127;
    float lrf, lif; lam_f32(lre[ch], lim[ch], lrf, lif);
    double pr = (double)lrf, pi = (double)lif;
#pragma unroll
    for (int s = 0; s < 8; ++s) { double nr = pr*pr - pi*pi, ni = 2.0*pr*pi; pr = nr; pi = ni; } // lambda^256
    float2 c0 = x0p[chain];
    double cr = (double)c0.x, ci = (double)c0.y;
#pragma unroll
    for (int s = 0; s < SEGN; ++s) {
        CarrySup[(size_t)s * 4096 + chain] = make_float2((float)cr, (float)ci);
        float2 e = Esup[(size_t)s * 4096 + chain];
        double nr = pr * cr - pi * ci + (double)e.x;
        double ni = pi * cr + pr * ci + (double)e.y;
        cr = nr; ci = ni;
    }
}

__global__ __launch_bounds__(256) void k_cexp(
    const float* __restrict__ lre, const float* __restrict__ lim,
    const float2* __restrict__ E, const float2* __restrict__ CarrySup,
    float2* __restrict__ Carry)
{
    int g = blockIdx.x * 256 + threadIdx.x;
    int chain = g & 4095, seg = g >> 12, ch = chain & 127;
    float lrf, lif; lam_f32(lre[ch], lim[ch], lrf, lif);
    double pr = (double)lrf, pi = (double)lif;
#pragma unroll
    for (int s = 0; s < 3; ++s) { double nr = pr*pr - pi*pi, ni = 2.0*pr*pi; pr = nr; pi = ni; } // lambda^8
    float2 cc = CarrySup[(size_t)seg * 4096 + chain];
    double cr = (double)cc.x, ci = (double)cc.y;
#pragma unroll 8
    for (int j = 0; j < CPS; ++j) {
        size_t idx = ((size_t)seg * CPS + j) * 4096 + chain;
        Carry[idx] = make_float2((float)cr, (float)ci);
        float2 e = E[idx];
        double nr = pr * cr - pi * ci + (double)e.x;
        double ni = pi * cr + pr * ci + (double)e.y;
        cr = nr; ci = ni;
    }
}

// ---------------------------------------------------------------------------
// Pass 2: seeded scan + fused output GEMM, both split-bf16.
// v2: LDS shrunk to EXACTLY 81920 B (sU 64x128, sX 64x512, zero pad,
// XOR chunk swizzle) -> 2 blocks/CU. U(sub+1) prefetched during MFMA phase.
// Per sub: [cvt+write sU(sub) -> out-GEMM(sub-1)] -> bar
//          -> [prefetch U(sub+1) ; Bu MFMA + scan + dump sX] -> bar.
// ---------------------------------------------------------------------------
__global__ __launch_bounds__(256, 1) void k_pass2(
    const float* __restrict__ U,
    const unsigned short* __restrict__ Bph, const unsigned short* __restrict__ Bpl,
    const unsigned short* __restrict__ Wph, const unsigned short* __restrict__ Wpl,
    const float* __restrict__ lre, const float* __restrict__ lim,
    const float* __restrict__ bx2y,
    const float2* __restrict__ Carry, float* __restrict__ Y)
{
    __shared__ __align__(16) unsigned short sU[64 * 128];   // 16384 B, swizzled
    __shared__ __align__(16) unsigned short sX[64 * 512];   // 65536 B, swizzled

    const int tid = threadIdx.x, w = tid >> 6, lane = tid & 63;
    const int l31 = lane & 31, kh = lane >> 5;
    const int c = blockIdx.x;
    const int ch = w * 32 + l31;             // scan channel
    const int mtile = w & 1, ntile = w >> 1; // out-GEMM tile mapping

    float lr, li; lam_f32(lre[ch], lim[ch], lr, li);
    float ybias = bx2y[ntile * 32 + l31];

    bf16x8 bfh[2][4], bfl[2][4];
#pragma unroll
    for (int nt = 0; nt < 2; ++nt)
#pragma unroll
        for (int kk = 0; kk < 4; ++kk) {
            bfh[nt][kk] = ldfrag(&Bph[(size_t)(nt * HH + ch) * NUU + kk * 16 + kh * 8]);
            bfl[nt][kk] = ldfrag(&Bpl[(size_t)(nt * HH + ch) * NUU + kk * 16 + kh * 8]);
        }

    // W fragments (hi + lo); compiler keeps/remats as it sees fit (L2-hot)
    bf16x8 wfh[16], wfl[16];
#pragma unroll
    for (int kk = 0; kk < 16; ++kk) {
        wfh[kk] = ldfrag(&Wph[(size_t)(ntile * 32 + l31) * NHH + kk * 16 + kh * 8]);
        wfl[kk] = ldfrag(&Wpl[(size_t)(ntile * 32 + l31) * NHH + kk * 16 + kh * 8]);
    }

    // Seed from Carry
    float zr[16], zi[16];
#pragma unroll
    for (int r = 0; r < 16; ++r) {
        float2 v = Carry[(size_t)c * 4096 + crow(r, lane) * HH + ch];
        zr[r] = v.x; zi[r] = v.y;
    }

    const int srow = tid >> 2, sus = (tid & 3) * 16;
    const int sb = srow & 31, stoff = srow >> 5;
    const float* ubase = U + (size_t)sb * NUU + sus;

    // prefetch sub 0
    float4 f0, f1, f2, f3;
    {
        const float4* sp = (const float4*)(ubase + (size_t)(c * LCH + stoff) * (NBB * NUU));
        f0 = sp[0]; f1 = sp[1]; f2 = sp[2]; f3 = sp[3];
    }

    for (int sub = 0; sub < 4; ++sub) {
        {   // convert + write sU (swizzled)
            bf16x8 h0, h1, l0, l1;
            CVT(f0.x, h0[0], l0[0]); CVT(f0.y, h0[1], l0[1]); CVT(f0.z, h0[2], l0[2]); CVT(f0.w, h0[3], l0[3]);
            CVT(f1.x, h0[4], l0[4]); CVT(f1.y, h0[5], l0[5]); CVT(f1.z, h0[6], l0[6]); CVT(f1.w, h0[7], l0[7]);
            CVT(f2.x, h1[0], l1[0]); CVT(f2.y, h1[1], l1[1]); CVT(f2.z, h1[2], l1[2]); CVT(f2.w, h1[3], l1[3]);
            CVT(f3.x, h1[4], l1[4]); CVT(f3.y, h1[5], l1[5]); CVT(f3.z, h1[6], l1[6]); CVT(f3.w, h1[7], l1[7]);
            *(bf16x8*)&sU[swzU(srow, sus)]          = h0;
            *(bf16x8*)&sU[swzU(srow, sus + 8)]      = h1;
            *(bf16x8*)&sU[swzU(srow, 64 + sus)]     = l0;
            *(bf16x8*)&sU[swzU(srow, 64 + sus + 8)] = l1;
        }

        if (sub > 0) {  // out-GEMM for sub-1 (reads sX written before last barrier)
            f32x16 ya0, ya1, ya2;
#pragma unroll
            for (int r = 0; r < 16; ++r) { ya0[r] = 0.f; ya1[r] = 0.f; ya2[r] = 0.f; }
#pragma unroll
            for (int kk = 0; kk < 16; ++kk) {
                bf16x8 xah = ldfrag(&sX[swzX(mtile * 32 + l31, kk * 16 + kh * 8)]);
                bf16x8 xal = ldfrag(&sX[swzX(mtile * 32 + l31, 256 + kk * 16 + kh * 8)]);
                ya0 = __builtin_amdgcn_mfma_f32_32x32x16_bf16(xah, wfh[kk], ya0, 0, 0, 0);
                ya1 = __builtin_amdgcn_mfma_f32_32x32x16_bf16(xal, wfh[kk], ya1, 0, 0, 0);
                ya2 = __builtin_amdgcn_mfma_f32_32x32x16_bf16(xah, wfl[kk], ya2, 0, 0, 0);
            }
            int t = c * LCH + (sub - 1) * 2 + mtile;
#pragma unroll
            for (int r = 0; r < 16; ++r)
                Y[((size_t)t * NBB + crow(r, lane)) * NYY + ntile * 32 + l31] =
                    (ya0[r] + ya1[r]) + ya2[r] + ybias;
        }
        __syncthreads();

        if (sub < 3) {   // prefetch next sub; lands under the MFMA phase
            const float4* sp = (const float4*)(ubase + (size_t)(c * LCH + (sub + 1) * 2 + stoff) * (NBB * NUU));
            f0 = sp[0]; f1 = sp[1]; f2 = sp[2]; f3 = sp[3];
        }

        // Bu MFMA (split 3-term)
        f32x16 acc[2][2];
#pragma unroll
        for (int mt = 0; mt < 2; ++mt)
#pragma unroll
            for (int nt = 0; nt < 2; ++nt)
#pragma unroll
                for (int r = 0; r < 16; ++r) acc[mt][nt][r] = 0.f;

#pragma unroll
        for (int kk = 0; kk < 4; ++kk) {
            bf16x8 a0h = ldfrag(&sU[swzU(l31,      kk * 16 + kh * 8)]);
            bf16x8 a1h = ldfrag(&sU[swzU(32 + l31, kk * 16 + kh * 8)]);
            bf16x8 a0l = ldfrag(&sU[swzU(l31,      64 + kk * 16 + kh * 8)]);
            bf16x8 a1l = ldfrag(&sU[swzU(32 + l31, 64 + kk * 16 + kh * 8)]);
            acc[0][0] = __builtin_amdgcn_mfma_f32_32x32x16_bf16(a0h, bfh[0][kk], acc[0][0], 0, 0, 0);
            acc[0][1] = __builtin_amdgcn_mfma_f32_32x32x16_bf16(a0h, bfh[1][kk], acc[0][1], 0, 0, 0);
            acc[1][0] = __builtin_amdgcn_mfma_f32_32x32x16_bf16(a1h, bfh[0][kk], acc[1][0], 0, 0, 0);
            acc[1][1] = __builtin_amdgcn_mfma_f32_32x32x16_bf16(a1h, bfh[1][kk], acc[1][1], 0, 0, 0);
            acc[0][0] = __builtin_amdgcn_mfma_f32_32x32x16_bf16(a0l, bfh[0][kk], acc[0][0], 0, 0, 0);
            acc[0][1] = __builtin_amdgcn_mfma_f32_32x32x16_bf16(a0l, bfh[1][kk], acc[0][1], 0, 0, 0);
            acc[1][0] = __builtin_amdgcn_mfma_f32_32x32x16_bf16(a1l, bfh[0][kk], acc[1][0], 0, 0, 0);
            acc[1][1] = __builtin_amdgcn_mfma_f32_32x32x16_bf16(a1l, bfh[1][kk], acc[1][1], 0, 0, 0);
            acc[0][0] = __builtin_amdgcn_mfma_f32_32x32x16_bf16(a0h, bfl[0][kk], acc[0][0], 0, 0, 0);
            acc[0][1] = __builtin_amdgcn_mfma_f32_32x32x16_bf16(a0h, bfl[1][kk], acc[0][1], 0, 0, 0);
            acc[1][0] = __builtin_amdgcn_mfma_f32_32x32x16_bf16(a1h, bfl[0][kk], acc[1][0], 0, 0, 0);
            acc[1][1] = __builtin_amdgcn_mfma_f32_32x32x16_bf16(a1h, bfl[1][kk], acc[1][1], 0, 0, 0);
        }

        // Scan + split hi/lo dump (two b32 per (mt,r)), swizzled
#pragma unroll
        for (int mt = 0; mt < 2; ++mt)
#pragma unroll
            for (int r = 0; r < 16; ++r) {
                float t0 = fmaf(lr, zr[r], acc[mt][0][r]); t0 = fmaf(-li, zi[r], t0);
                float t1 = fmaf(li, zr[r], acc[mt][1][r]); t1 = fmaf(lr, zi[r], t1);
                zr[r] = t0; zi[r] = t1;
                bf16x2 hv, lv;
                { __bf16 _h = (__bf16)t0; hv[0] = _h; lv[0] = (__bf16)(t0 - (float)_h); }
                { __bf16 _h = (__bf16)t1; hv[1] = _h; lv[1] = (__bf16)(t1 - (float)_h); }
                int row = mt * 32 + crow(r, lane);
                *(bf16x2*)&sX[swzX(row, w * 64 + 2 * l31)]       = hv;
                *(bf16x2*)&sX[swzX(row, 256 + w * 64 + 2 * l31)] = lv;
            }
        __syncthreads();
    }

    // Drain: out-GEMM for sub=3
    {
        f32x16 ya0, ya1, ya2;
#pragma unroll
        for (int r = 0; r < 16; ++r) { ya0[r] = 0.f; ya1[r] = 0.f; ya2[r] = 0.f; }
#pragma unroll
        for (int kk = 0; kk < 16; ++kk) {
            bf16x8 xah = ldfrag(&sX[swzX(mtile * 32 + l31, kk * 16 + kh * 8)]);
            bf16x8 xal = ldfrag(&sX[swzX(mtile * 32 + l31, 256 + kk * 16 + kh * 8)]);
            ya0 = __builtin_amdgcn_mfma_f32_32x32x16_bf16(xah, wfh[kk], ya0, 0, 0, 0);
            ya1 = __builtin_amdgcn_mfma_f32_32x32x16_bf16(xal, wfh[kk], ya1, 0, 0, 0);
            ya2 = __builtin_amdgcn_mfma_f32_32x32x16_bf16(xah, wfl[kk], ya2, 0, 0, 0);
        }
        int t = c * LCH + 3 * 2 + mtile;
#pragma unroll
        for (int r = 0; r < 16; ++r)
            Y[((size_t)t * NBB + crow(r, lane)) * NYY + ntile * 32 + l31] =
                (ya0[r] + ya1[r]) + ya2[r] + ybias;
    }
}

// ---------------------------------------------------------------------------
extern "C" void kernel_launch(void* const* d_in, const int* in_sizes, int n_in,
                              void* d_out, int out_size, void* d_ws, size_t ws_size,
                              hipStream_t stream) {
    const float* y0    = (const float*)d_in[0];
    const float* U     = (const float*)d_in[1];
    const float* lre   = (const float*)d_in[2];
    const float* lim   = (const float*)d_in[3];
    const float* B     = (const float*)d_in[4];
    const float* W_y2x = (const float*)d_in[5];
    const float* b_y2x = (const float*)d_in[6];
    const float* W_x2y = (const float*)d_in[7];
    const float* b_x2y = (const float*)d_in[8];
    float* Y = (float*)d_out;

    char* p = (char*)d_ws;
    float2* E        = (float2*)p; p += (size_t)CCH * 4096 * sizeof(float2);   // 16 MB
    float2* Carry    = (float2*)p; p += (size_t)CCH * 4096 * sizeof(float2);   // 16 MB
    float2* Esup     = (float2*)p; p += (size_t)SEGN * 4096 * sizeof(float2);  // 512 KB
    float2* CarrySup = (float2*)p; p += (size_t)SEGN * 4096 * sizeof(float2);  // 512 KB
    float2* x0p      = (float2*)p; p += (size_t)4096 * sizeof(float2);         // 32 KB
    unsigned short* Bph = (unsigned short*)p; p += 16384 * sizeof(unsigned short);
    unsigned short* Bpl = (unsigned short*)p; p += 16384 * sizeof(unsigned short);
    unsigned short* Wph = (unsigned short*)p; p += 16384 * sizeof(unsigned short);
    unsigned short* Wpl = (unsigned short*)p; p += 16384 * sizeof(unsigned short);

    k_prep <<<dim3(96),  dim3(256), 0, stream>>>(B, W_x2y, y0, W_y2x, b_y2x, Bph, Bpl, Wph, Wpl, x0p);
    k_pass1<<<dim3(CCH), dim3(256), 0, stream>>>(U, Bph, Bpl, lre, lim, E);
    k_cseg <<<dim3(256), dim3(256), 0, stream>>>(lre, lim, E, Esup);
    k_csup <<<dim3(16),  dim3(256), 0, stream>>>(lre, lim, x0p, Esup, CarrySup);
    k_cexp <<<dim3(256), dim3(256), 0, stream>>>(lre, lim, E, CarrySup, Carry);
    k_pass2<<<dim3(CCH), dim3(256), 0, stream>>>(U, Bph, Bpl, Wph, Wpl, lre, lim, b_x2y, Carry, Y);
}